// Round 8
// baseline (5768.586 us; speedup 1.0000x reference)
//
#include <hip/hip_runtime.h>
#include <stdint.h>

#define BATCHES 32
#define NPT     100000
#define NSAMP   1024
#define GPB     8          // blocks (groups) per batch -> 256 blocks = 1/CU
#define TPB     1024
#define PPB     12500      // points per block (8*12500 = 100000)
#define PPT     13         // k=0..11 full (12288), k=12 only tid<212
#define TAILT   212
#define NW      (TPB/64)   // 16 waves per block

typedef unsigned long long u64;
typedef unsigned int u32;

// Record per (parity, batch, group): 4 u64 (32B, w3 pad). Self-validating
// tagged words (R7 scheme): tag2 = (((it+1)>>1)+1)&3 in bits [63:62] of each
// word; only same-parity versions it-1 / it+1 are observable -> tag2
// distinguishes; memset-0 state is invalid for the first expected tag (=1).
//   w0 = tag2 | key[61:0]
//   w1 = tag2 | key[63:62]<<60 | x<<28 | y>>4
//   w2 = tag2 | (y&0xF)<<58   | z<<26 | idx<<9
#define WS_BYTES (2 * BATCHES * GPB * 4 * 8)   // 16 KB

__device__ __forceinline__ void red_ki(u64& key, u32& idx, int off) {
    u64 ok = __shfl_xor(key, off, 64);
    u32 oi = __shfl_xor(idx, off, 64);
    if (ok > key || (ok == key && oi < idx)) { key = ok; idx = oi; }
}

__device__ __forceinline__ void red_step(u64& key, u32& idx, float& x, float& y, float& z, int off) {
    u64   ok = __shfl_xor(key, off, 64);
    u32   oi = __shfl_xor(idx, off, 64);
    float ox = __shfl_xor(x, off, 64);
    float oy = __shfl_xor(y, off, 64);
    float oz = __shfl_xor(z, off, 64);
    if (ok > key || (ok == key && oi < idx)) { key = ok; idx = oi; x = ox; y = oy; z = oz; }
}

// L2-served poll loads: sc0 bypasses the (non-coherent) per-CU L1 but is
// satisfied by the XCD's shared L2 -> ~200-300 cyc when producer is same-XCD
// (plain write-back store). Cross-XCD case is rescued by the periodic
// agent-scope loads in the poll loop (correctness never depends on the
// blockIdx->XCD mapping).
__device__ __forceinline__ void load3_sc0(u64 addr, u64& a, u64& b, u64& c) {
    asm volatile("global_load_dwordx2 %0, %3, off sc0\n\t"
                 "global_load_dwordx2 %1, %3, off offset:8 sc0\n\t"
                 "global_load_dwordx2 %2, %3, off offset:16 sc0\n\t"
                 "s_waitcnt vmcnt(0)"
                 : "=&v"(a), "=&v"(b), "=&v"(c)
                 : "v"(addr)
                 : "memory");
}

__global__ void
__attribute__((amdgpu_flat_work_group_size(TPB, TPB), amdgpu_waves_per_eu(4, 4)))
fps_kernel(const float* __restrict__ coord,
           const int* __restrict__ seed_raw,
           float* __restrict__ out,
           u64* __restrict__ rec)
{
    const int tid  = threadIdx.x;
    const int lane = tid & 63;
    const int wid  = tid >> 6;
    // All 8 groups of a batch share blockIdx%8 -> same XCD under round-robin
    // dispatch (speed heuristic only; rescue path covers the alternative).
    const int b    = (int)blockIdx.x & 31;
    const int g    = (int)blockIdx.x >> 5;
    const int base = g * PPB;
    const float* cb = coord + (size_t)b * (NPT * 3);

    __shared__ u64   wkey[NW];
    __shared__ u32   widx[NW];
    __shared__ float wx[NW], wy[NW], wz[NW];
    __shared__ u32   s_win;
    __shared__ float s_cx, s_cy, s_cz;

    // Seed index (robust to int32 or int64 materialization of farthest_init).
    int odd = 0;
    #pragma unroll
    for (int i = 1; i < 32; i += 2) odd |= seed_raw[i];
    int cur = (odd == 0) ? seed_raw[2 * b] : seed_raw[b];

    float cx = cb[(size_t)cur * 3 + 0];
    float cy = cb[(size_t)cur * 3 + 1];
    float cz = cb[(size_t)cur * 3 + 2];

    // Coords (39 f32) AND running min-distance (13 f64) in registers
    // (overflow spills to AGPRs on the unified file, not scratch - R6 data).
    float  px[PPT], py[PPT], pz[PPT];
    double d[PPT];
    #pragma unroll
    for (int k = 0; k < PPT; ++k) {
        bool v = (k < 12) || (tid < TAILT);
        int gi = base + (v ? (k * TPB + tid) : 0);
        px[k] = v ? cb[(size_t)gi * 3 + 0] : 0.f;
        py[k] = v ? cb[(size_t)gi * 3 + 1] : 0.f;
        pz[k] = v ? cb[(size_t)gi * 3 + 2] : 0.f;
        d[k]  = v ? 1.0e10 : 0.0;   // fake points can never win argmax
    }

    float* cent_out = out;                       // (B, 1024) as float
    float* samp_out = out + BATCHES * NSAMP;     // (B, 1024, 3)

    for (int it = 0; it < NSAMP; ++it) {
        // Outputs written by the otherwise-idle wave 1 (off the sync path).
        if (g == 0 && wid == 1 && lane == 0) {
            cent_out[b * NSAMP + it] = (float)cur;
            size_t so = ((size_t)b * NSAMP + it) * 3;
            samp_out[so + 0] = cx; samp_out[so + 1] = cy; samp_out[so + 2] = cz;
        }

        const double cxd = (double)cx, cyd = (double)cy, czd = (double)cz;

        // f64 update + per-thread argmax. Explicit _rn ops forbid FMA
        // contraction; sum order ((dx^2+dy^2)+dz^2) matches np.sum(axis=-1).
        double bd = -1.0; u32 bi = 0; float bx = 0.f, by = 0.f, bz = 0.f;
        #pragma unroll
        for (int k = 0; k < PPT; ++k) {
            if (k == 12 && tid >= TAILT) break;
            double dx = __dsub_rn((double)px[k], cxd);
            double dy = __dsub_rn((double)py[k], cyd);
            double dz = __dsub_rn((double)pz[k], czd);
            double d2 = __dadd_rn(__dadd_rn(__dmul_rn(dx, dx), __dmul_rn(dy, dy)),
                                  __dmul_rn(dz, dz));
            double nd = fmin(d[k], d2);
            d[k] = nd;
            bool gt = nd > bd;       // strict > keeps smallest k (== smallest idx)
            bd = gt ? nd : bd;
            bi = gt ? (u32)(base + k * TPB + tid) : bi;
            bx = gt ? px[k] : bx;
            by = gt ? py[k] : by;
            bz = gt ? pz[k] : bz;
        }
        u64 key = (u64)__double_as_longlong(bd);   // bd >= 0 -> monotone bits

        // LEAN wave butterfly: (key, idx) only (3 dwords/step, not 6). The
        // unique winning lane (bi values are distinct) deposits its coords.
        u64 wk = key; u32 wi = bi;
        red_ki(wk, wi, 32); red_ki(wk, wi, 16); red_ki(wk, wi, 8);
        red_ki(wk, wi, 4);  red_ki(wk, wi, 2);  red_ki(wk, wi, 1);
        if (wi == bi) { wkey[wid] = wk; widx[wid] = wi; wx[wid] = bx; wy[wid] = by; wz[wid] = bz; }
        __syncthreads();

        if (wid == 0) {
            // Block reduce over 16 wave partials (lanes 0..15).
            u64   k2 = (lane < NW) ? wkey[lane] : 0ull;
            u32   i2 = (lane < NW) ? widx[lane] : 0xFFFFFFFFu;
            float x2 = (lane < NW) ? wx[lane] : 0.f;
            float y2 = (lane < NW) ? wy[lane] : 0.f;
            float z2 = (lane < NW) ? wz[lane] : 0.f;
            red_step(k2, i2, x2, y2, z2, 8); red_step(k2, i2, x2, y2, z2, 4);
            red_step(k2, i2, x2, y2, z2, 2); red_step(k2, i2, x2, y2, z2, 1);

            const int s = it & 1;                       // parity double-buffer
            u64* slot = rec + ((size_t)(s * BATCHES + b) * GPB) * 4;
            const u64 t2 = (u64)((((it + 1) >> 1) + 1) & 3);

            if (lane == 0) {
                u32 xb = __float_as_uint(x2), yb = __float_as_uint(y2), zb = __float_as_uint(z2);
                u64 w0 = (t2 << 62) | (k2 & 0x3FFFFFFFFFFFFFFFull);
                u64 w1 = (t2 << 62) | ((k2 >> 62) << 60) | ((u64)xb << 28) | (u64)(yb >> 4);
                u64 w2 = (t2 << 62) | ((u64)(yb & 0xFu) << 58) | ((u64)zb << 26) | ((u64)i2 << 9);
                u64* r = slot + g * 4;
                // Fast path: plain write-back stores -> resident in this XCD's
                // L2, visible to same-XCD sc0 pollers at L2 latency.
                volatile u64* pr = (volatile u64*)r;
                pr[0] = w0; pr[1] = w1; pr[2] = w2;
                // Correctness path: agent-scope stores -> LLC, visible device-
                // wide for the rescue loads. Same values; order irrelevant
                // (self-validating words).
                __hip_atomic_store(&r[0], w0, __ATOMIC_RELAXED, __HIP_MEMORY_SCOPE_AGENT);
                __hip_atomic_store(&r[1], w1, __ATOMIC_RELAXED, __HIP_MEMORY_SCOPE_AGENT);
                __hip_atomic_store(&r[2], w2, __ATOMIC_RELAXED, __HIP_MEMORY_SCOPE_AGENT);
            }

            // Poll: lanes 0..7 read group lane's 3 words. Mostly sc0 (L2)
            // loads; every 8th round agent-scope (LLC) as cross-XCD rescue.
            u64 w0 = 0, w1 = 0, w2 = 0;
            u64 ra = (u64)(uintptr_t)(slot + lane * 4);
            for (int spin = 0; ; ++spin) {
                bool ok = true;
                if (lane < GPB) {
                    if ((spin & 7) == 7) {
                        u64* r = (u64*)(uintptr_t)ra;
                        w0 = __hip_atomic_load(&r[0], __ATOMIC_RELAXED, __HIP_MEMORY_SCOPE_AGENT);
                        w1 = __hip_atomic_load(&r[1], __ATOMIC_RELAXED, __HIP_MEMORY_SCOPE_AGENT);
                        w2 = __hip_atomic_load(&r[2], __ATOMIC_RELAXED, __HIP_MEMORY_SCOPE_AGENT);
                    } else {
                        load3_sc0(ra, w0, w1, w2);
                    }
                    ok = ((w0 >> 62) == t2) & ((w1 >> 62) == t2) & ((w2 >> 62) == t2);
                }
                if (__ballot(ok) == ~0ull) break;
                __builtin_amdgcn_s_sleep(1);
            }

            // Unpack + final butterfly over 8 group records.
            u64   k3 = 0ull; u32 i3 = 0xFFFFFFFFu;
            float x3 = 0.f, y3 = 0.f, z3 = 0.f;
            if (lane < GPB) {
                k3 = (w0 & 0x3FFFFFFFFFFFFFFFull) | (((w1 >> 60) & 3ull) << 62);
                u32 xb = (u32)(w1 >> 28);
                u32 yb = (u32)(((w1 & 0xFFFFFFFull) << 4) | ((w2 >> 58) & 0xFull));
                u32 zb = (u32)(w2 >> 26);
                i3 = (u32)((w2 >> 9) & 0x1FFFFu);
                x3 = __uint_as_float(xb);
                y3 = __uint_as_float(yb);
                z3 = __uint_as_float(zb);
            }
            red_step(k3, i3, x3, y3, z3, 4); red_step(k3, i3, x3, y3, z3, 2); red_step(k3, i3, x3, y3, z3, 1);
            if (lane == 0) { s_win = i3; s_cx = x3; s_cy = y3; s_cz = z3; }
        }
        __syncthreads();
        cur = (int)s_win; cx = s_cx; cy = s_cy; cz = s_cz;
    }
}

extern "C" void kernel_launch(void* const* d_in, const int* in_sizes, int n_in,
                              void* d_out, int out_size, void* d_ws, size_t ws_size,
                              hipStream_t stream)
{
    const float* coord = (const float*)d_in[0];
    const int*   seed  = (const int*)d_in[1];
    float* out = (float*)d_out;
    u64* rec = (u64*)d_ws;

    hipMemsetAsync(d_ws, 0, WS_BYTES, stream);
    fps_kernel<<<dim3(BATCHES * GPB), dim3(TPB), 0, stream>>>(coord, seed, out, rec);
}

// Round 9
// 4389.698 us; speedup vs baseline: 1.3141x; 1.3141x over previous
//
#include <hip/hip_runtime.h>
#include <stdint.h>

#define BATCHES 32
#define NPT     100000
#define NSAMP   1024
#define GPB     16         // groups (blocks) per batch
#define NPAIR   16         // batch pairs; block serves batches (p, p+16)
#define TPB     1024       // 16 waves: 0..14 compute (960 thr), 15 = sync wave
#define NCW     15         // compute waves
#define CTH     (NCW*64)   // 960 compute threads
#define PPB     6250       // points per (batch, group)
#define PPT     7          // ceil(6250/960): k<6 full (5760), k==6 ct<490
#define TAILT   490

typedef unsigned long long u64;
typedef unsigned int u32;

// Mailbox rec[tag&1][batch][group][4 u64] — R7 self-validating tagged words.
// tag2(v) = ((v>>1)+1)&3 in bits [63:62] of every word; within a slot only
// versions v / v+2 are observable and their tag2 differ; memset-0 is invalid.
//   w0 = tag2 | key[61:0]
//   w1 = tag2 | key[63:62]<<60 | x<<28 | y>>4
//   w2 = tag2 | (y&0xF)<<58   | z<<26 | idx<<9     (idx: 17 bits)
#define WS_BYTES (2 * BATCHES * GPB * 4 * 8)   // 32 KB

__device__ __forceinline__ void red_ki(u64& key, u32& idx, int off) {
    u64 ok = __shfl_xor(key, off, 64);
    u32 oi = __shfl_xor(idx, off, 64);
    if (ok > key || (ok == key && oi < idx)) { key = ok; idx = oi; }
}

__device__ __forceinline__ void red_step(u64& key, u32& idx, float& x, float& y, float& z, int off) {
    u64   ok = __shfl_xor(key, off, 64);
    u32   oi = __shfl_xor(idx, off, 64);
    float ox = __shfl_xor(x, off, 64);
    float oy = __shfl_xor(y, off, 64);
    float oz = __shfl_xor(z, off, 64);
    if (ok > key || (ok == key && oi < idx)) { key = ok; idx = oi; x = ox; y = oy; z = oz; }
}

__global__ void
__attribute__((amdgpu_flat_work_group_size(TPB, TPB), amdgpu_waves_per_eu(4, 4)))
fps_kernel(const float* __restrict__ coord,
           const int* __restrict__ seed_raw,
           float* __restrict__ out,
           u64* __restrict__ rec)
{
    const int tid  = threadIdx.x;
    const int lane = tid & 63;
    const int wid  = tid >> 6;
    const int p    = (int)blockIdx.x & (NPAIR - 1);   // pair id
    const int g    = (int)blockIdx.x >> 4;            // group 0..15
    const int base = g * PPB;
    const int bA = p, bB = p + NPAIR;

    // Winner words per (batch-slot, parity): 2 words, tag2-versioned like rec.
    //   v0 = tag2 | x<<30 | y>>2
    //   v1 = tag2 | (y&3)<<60 | z<<28 | idx<<11
    __shared__ u64 winw[2][2][2];   // [xb][t&1][word]
    __shared__ u32 sbar[8];         // rolling soft-barrier counters (monotone)
    __shared__ u64   pkey[2][NCW];  // wave partials, double-buffered by phase
    __shared__ u32   pidx[2][NCW];
    __shared__ float pxs[2][NCW], pys[2][NCW], pzs[2][NCW];

    if (tid < 8) { sbar[tid] = 0; ((u64*)winw)[tid] = 0ull; }
    __syncthreads();   // only block-wide barrier (before wave-role split)

    float* cent_out = out;                       // (B, 1024) as float
    float* samp_out = out + BATCHES * NSAMP;     // (B, 1024, 3)

    if (wid == NCW) {
        // ---------------- SYNC WAVE: poll mailbox, deliver winners to LDS ---
        for (int t = 1; t < NSAMP; ++t) {
            #pragma unroll
            for (int xb = 0; xb < 2; ++xb) {
                const int batch = xb ? bB : bA;
                u64* slot = rec + ((size_t)((t & 1) * BATCHES + batch) * GPB) * 4;
                const u64 t2 = (u64)(((t >> 1) + 1) & 3);
                const bool mine = lane < 3 * GPB;   // 48 poll lanes
                u64* wp = slot + (mine ? ((lane / 3) * 4 + (lane % 3)) : 0);
                u64 w = 0;
                for (;;) {
                    bool ok = true;
                    if (mine) {
                        w = __hip_atomic_load(wp, __ATOMIC_RELAXED, __HIP_MEMORY_SCOPE_AGENT);
                        ok = (w >> 62) == t2;
                    }
                    if (__ballot(ok) == ~0ull) break;
                    __builtin_amdgcn_s_sleep(1);
                }
                const int li = lane & 15;
                u64 w0 = __shfl(w, 3 * li + 0, 64);
                u64 w1 = __shfl(w, 3 * li + 1, 64);
                u64 w2 = __shfl(w, 3 * li + 2, 64);
                u64 k3 = 0ull; u32 i3 = 0xFFFFFFFFu; float x3 = 0.f, y3 = 0.f, z3 = 0.f;
                if (lane < GPB) {
                    k3 = (w0 & 0x3FFFFFFFFFFFFFFFull) | (((w1 >> 60) & 3ull) << 62);
                    u32 xbt = (u32)(w1 >> 28);
                    u32 ybt = (u32)(((w1 & 0xFFFFFFFull) << 4) | ((w2 >> 58) & 0xFull));
                    u32 zbt = (u32)(w2 >> 26);
                    i3 = (u32)((w2 >> 9) & 0x1FFFFu);
                    x3 = __uint_as_float(xbt); y3 = __uint_as_float(ybt); z3 = __uint_as_float(zbt);
                }
                red_step(k3, i3, x3, y3, z3, 8); red_step(k3, i3, x3, y3, z3, 4);
                red_step(k3, i3, x3, y3, z3, 2); red_step(k3, i3, x3, y3, z3, 1);
                if (lane == 0) {
                    u32 xbt = __float_as_uint(x3), ybt = __float_as_uint(y3), zbt = __float_as_uint(z3);
                    u64 v0 = (t2 << 62) | ((u64)xbt << 30) | (u64)(ybt >> 2);
                    u64 v1 = (t2 << 62) | ((u64)(ybt & 3u) << 60) | ((u64)zbt << 28) | ((u64)i3 << 11);
                    __hip_atomic_store(&winw[xb][t & 1][0], v0, __ATOMIC_RELAXED, __HIP_MEMORY_SCOPE_WORKGROUP);
                    __hip_atomic_store(&winw[xb][t & 1][1], v1, __ATOMIC_RELAXED, __HIP_MEMORY_SCOPE_WORKGROUP);
                }
            }
        }
        return;
    }

    // ---------------- COMPUTE WAVES (0..14) --------------------------------
    const int ct = tid;   // 0..959
    const float* cbA = coord + (size_t)bA * (NPT * 3);
    const float* cbB = coord + (size_t)bB * (NPT * 3);

    // Seed indices (robust to int32 / int64 farthest_init materialization).
    int odd = 0;
    #pragma unroll
    for (int i = 1; i < 32; i += 2) odd |= seed_raw[i];
    u32 scur[2]; float scx[2], scy[2], scz[2];
    scur[0] = (u32)((odd == 0) ? seed_raw[2 * bA] : seed_raw[bA]);
    scur[1] = (u32)((odd == 0) ? seed_raw[2 * bB] : seed_raw[bB]);
    scx[0] = cbA[(size_t)scur[0] * 3 + 0]; scy[0] = cbA[(size_t)scur[0] * 3 + 1]; scz[0] = cbA[(size_t)scur[0] * 3 + 2];
    scx[1] = cbB[(size_t)scur[1] * 3 + 0]; scy[1] = cbB[(size_t)scur[1] * 3 + 1]; scz[1] = cbB[(size_t)scur[1] * 3 + 2];

    // Coords (2x21 f32) + running f64 min-distance (2x7) in registers
    // (overflow rides the unified AGPR file, not scratch — R6 data).
    float  px[2][PPT], py[2][PPT], pz[2][PPT];
    double d[2][PPT];
    #pragma unroll
    for (int xb = 0; xb < 2; ++xb) {
        const float* cb = xb ? cbB : cbA;
        #pragma unroll
        for (int k = 0; k < PPT; ++k) {
            bool v = (k < PPT - 1) || (ct < TAILT);
            int gi = base + (v ? (k * CTH + ct) : 0);
            px[xb][k] = v ? cb[(size_t)gi * 3 + 0] : 0.f;
            py[xb][k] = v ? cb[(size_t)gi * 3 + 1] : 0.f;
            pz[xb][k] = v ? cb[(size_t)gi * 3 + 2] : 0.f;
            d[xb][k]  = v ? 1.0e10 : 0.0;   // fakes can never win argmax
        }
    }

    for (int t = 0; t < NSAMP; ++t) {
        #pragma unroll
        for (int xb = 0; xb < 2; ++xb) {
            const int batch = xb ? bB : bA;
            const int pi = 2 * t + xb;
            u32 cur; float cx, cy, cz;
            if (t == 0) {
                cur = scur[xb]; cx = scx[xb]; cy = scy[xb]; cz = scz[xb];
            } else {
                const u64 t2 = (u64)(((t >> 1) + 1) & 3);
                u64 v0, v1;
                for (;;) {   // LDS spin — sync wave delivers well ahead
                    v0 = __hip_atomic_load(&winw[xb][t & 1][0], __ATOMIC_RELAXED, __HIP_MEMORY_SCOPE_WORKGROUP);
                    v1 = __hip_atomic_load(&winw[xb][t & 1][1], __ATOMIC_RELAXED, __HIP_MEMORY_SCOPE_WORKGROUP);
                    if (((v0 >> 62) == t2) & ((v1 >> 62) == t2)) break;
                }
                u32 xbt = (u32)(v0 >> 30);
                u32 ybt = (u32)(((v0 & 0x3FFFFFFFull) << 2) | ((v1 >> 60) & 3ull));
                u32 zbt = (u32)(v1 >> 28);
                cur = (u32)((v1 >> 11) & 0x1FFFFu);
                cx = __uint_as_float(xbt); cy = __uint_as_float(ybt); cz = __uint_as_float(zbt);
            }
            if (g == 0 && wid == 1 && lane == 0) {
                cent_out[batch * NSAMP + t] = (float)cur;
                size_t so = ((size_t)batch * NSAMP + t) * 3;
                samp_out[so + 0] = cx; samp_out[so + 1] = cy; samp_out[so + 2] = cz;
            }
            if (t == NSAMP - 1) continue;   // last emit needs no update/publish

            // Exact f64 update + argmax (matches float64 numpy bitwise:
            // _rn ops forbid FMA; sum order ((dx^2+dy^2)+dz^2)).
            const double cxd = (double)cx, cyd = (double)cy, czd = (double)cz;
            double bd = -1.0; u32 bi = 0; float bx = 0.f, by = 0.f, bz = 0.f;
            #pragma unroll
            for (int k = 0; k < PPT; ++k) {
                if (k == PPT - 1 && ct >= TAILT) break;
                double dx = __dsub_rn((double)px[xb][k], cxd);
                double dy = __dsub_rn((double)py[xb][k], cyd);
                double dz = __dsub_rn((double)pz[xb][k], czd);
                double d2 = __dadd_rn(__dadd_rn(__dmul_rn(dx, dx), __dmul_rn(dy, dy)),
                                      __dmul_rn(dz, dz));
                double nd = fmin(d[xb][k], d2);
                d[xb][k] = nd;
                bool gt = nd > bd;   // strict > keeps smallest k (= smallest idx)
                bd = gt ? nd : bd;
                bi = gt ? (u32)(base + k * CTH + ct) : bi;
                bx = gt ? px[xb][k] : bx;
                by = gt ? py[xb][k] : by;
                bz = gt ? pz[xb][k] : bz;
            }
            u64 key = (u64)__double_as_longlong(bd);

            // Lean wave butterfly; unique winner lane deposits coords.
            u64 wk = key; u32 wi = bi;
            red_ki(wk, wi, 32); red_ki(wk, wi, 16); red_ki(wk, wi, 8);
            red_ki(wk, wi, 4);  red_ki(wk, wi, 2);  red_ki(wk, wi, 1);
            const int pb = pi & 1;
            if (wi == bi) { pkey[pb][wid] = wk; pidx[pb][wid] = wi;
                            pxs[pb][wid] = bx; pys[pb][wid] = by; pzs[pb][wid] = bz; }

            // Soft barrier over the 15 compute waves (rolling counters).
            if (lane == 0)
                __hip_atomic_fetch_add(&sbar[pi & 7], 1u, __ATOMIC_RELEASE, __HIP_MEMORY_SCOPE_WORKGROUP);
            const u32 tgt = (u32)(NCW * ((pi >> 3) + 1));
            while (__hip_atomic_load(&sbar[pi & 7], __ATOMIC_ACQUIRE, __HIP_MEMORY_SCOPE_WORKGROUP) < tgt) {}

            if (wid == 0) {
                u64   k2 = (lane < NCW) ? pkey[pb][lane] : 0ull;
                u32   i2 = (lane < NCW) ? pidx[pb][lane] : 0xFFFFFFFFu;
                float x2 = (lane < NCW) ? pxs[pb][lane] : 0.f;
                float y2 = (lane < NCW) ? pys[pb][lane] : 0.f;
                float z2 = (lane < NCW) ? pzs[pb][lane] : 0.f;
                red_step(k2, i2, x2, y2, z2, 8); red_step(k2, i2, x2, y2, z2, 4);
                red_step(k2, i2, x2, y2, z2, 2); red_step(k2, i2, x2, y2, z2, 1);
                if (lane == 0) {
                    const u32 v = (u32)(t + 1);          // tag value
                    const u64 t2p = (u64)(((v >> 1) + 1) & 3);
                    u64* r = rec + ((size_t)((v & 1) * BATCHES + batch) * GPB + g) * 4;
                    u32 xbt = __float_as_uint(x2), ybt = __float_as_uint(y2), zbt = __float_as_uint(z2);
                    u64 w0 = (t2p << 62) | (k2 & 0x3FFFFFFFFFFFFFFFull);
                    u64 w1 = (t2p << 62) | ((k2 >> 62) << 60) | ((u64)xbt << 28) | (u64)(ybt >> 4);
                    u64 w2 = (t2p << 62) | ((u64)(ybt & 0xFu) << 58) | ((u64)zbt << 26) | ((u64)i2 << 9);
                    __hip_atomic_store(&r[0], w0, __ATOMIC_RELAXED, __HIP_MEMORY_SCOPE_AGENT);
                    __hip_atomic_store(&r[1], w1, __ATOMIC_RELAXED, __HIP_MEMORY_SCOPE_AGENT);
                    __hip_atomic_store(&r[2], w2, __ATOMIC_RELAXED, __HIP_MEMORY_SCOPE_AGENT);
                }
            }
        }
    }
}

extern "C" void kernel_launch(void* const* d_in, const int* in_sizes, int n_in,
                              void* d_out, int out_size, void* d_ws, size_t ws_size,
                              hipStream_t stream)
{
    const float* coord = (const float*)d_in[0];
    const int*   seed  = (const int*)d_in[1];
    float* out = (float*)d_out;
    u64* rec = (u64*)d_ws;

    hipMemsetAsync(d_ws, 0, WS_BYTES, stream);
    fps_kernel<<<dim3(NPAIR * GPB), dim3(TPB), 0, stream>>>(coord, seed, out, rec);
}